// Round 6
// baseline (90.372 us; speedup 1.0000x reference)
//
#include <hip/hip_runtime.h>
#include <hip/hip_bf16.h>
#include <math.h>

// Shapes: B=32, C=128, O=128, K=3, L=4096, W=1, PAD=1, DIL=1
// out[b,o,i] = sum_kc Wr[kc,o] * G[b,kc,i],  kc = k*128+c (K=384)
// G[b,kc,i] = wae[b,k,i]*x[b,c,addr] + wbe[b,k,i]*x[b,c,addr+1]
//
// k_fused: per block (128-i tile, one b, all 128 o):
//   double-buffered LDS x-window [32c x 160i] fp32; next window's global
//   loads issued BEFORE compute (T14 async-stage), written after; ONE
//   barrier per phase. Interp via ds_read2; MFMA A-frags from L2.
//   Wave-uniform global-gather fallback when any addr exits the window.
//
// ws layout (bytes):
//   WrA @ 0       : bf16 A-frags, 8 m x 12 s x 64 lanes x 16B = 98304
//   wT  @ 98304   : float[128*32] transposed conv weights, wT[c*32+ch*3+tap]
//   addr2 @ 131072: int[32*3*4096]
//   wae @ 1703936 : float[32*3*4096]
//   wbe @ 3276800 : float[32*3*4096]

typedef __attribute__((ext_vector_type(8))) short bf16x8;
typedef __attribute__((ext_vector_type(4))) float f32x4;
typedef float f32x2u __attribute__((ext_vector_type(2), aligned(4)));

#define WIN 160
#define WPAD 161   // dword stride; 161%32=1 -> q-groups at +8 bank shifts, ~2-way

static __device__ inline unsigned short f2bf(float f) {
    __hip_bfloat16 h = __float2bfloat16(f);
    union { __hip_bfloat16 b; unsigned short u; } cv;
    cv.b = h;
    return cv.u;
}

// ---------- kernel 0: pack WrA (A-frags) + wT (transposed conv weights) ----------
// A-frag (m,s), lane l, elem e:  A[o = m*16+(l&15)][kc = s*32+(l>>4)*8+e]
__global__ __launch_bounds__(256) void k_wra(const float* __restrict__ w_reg,
                                             const float* __restrict__ w_off,
                                             const float* __restrict__ w_mod,
                                             unsigned short* __restrict__ WrA,
                                             float* __restrict__ wT) {
    int t = blockIdx.x * 256 + threadIdx.x;
    if (t < 8 * 12 * 64 * 8) {
        int e  = t & 7;
        int l  = (t >> 3) & 63;
        int ms = t >> 9;              // m*12 + s
        int m  = ms / 12;
        int s  = ms - m * 12;
        int o  = m * 16 + (l & 15);
        int kc = s * 32 + ((l >> 4) & 3) * 8 + e;
        int tap = kc >> 7;
        int c   = kc & 127;
        WrA[t] = f2bf(w_reg[(o * 128 + c) * 3 + tap]);
    } else if (t < 8 * 12 * 64 * 8 + 128 * 27) {
        int u = t - 8 * 12 * 64 * 8;
        int c = u / 27, r = u - c * 27;
        int ch = r / 3, tap = r - ch * 3;
        wT[c * 32 + r] = (ch < 6) ? w_off[(ch * 128 + c) * 3 + tap]
                                  : w_mod[((ch - 6) * 128 + c) * 3 + tap];
    }
}

// ---------- kernel 1: offset/mask conv, neighbors via shuffle ----------
// grid (32, 32): 128-i tiles, lane owns i,i+1. Wave wv sums c in [32wv,32wv+32).
__global__ __launch_bounds__(256) void k_prep(const float* __restrict__ x,
                                              const float* __restrict__ wT,
                                              const float* __restrict__ b_off,
                                              const float* __restrict__ b_mod,
                                              int* __restrict__ addr2,
                                              float* __restrict__ wae,
                                              float* __restrict__ wbe) {
    __shared__ float red[3 * 64 * 18];
    int t = threadIdx.x;
    int lane = t & 63;
    int wv = t >> 6;
    int b = blockIdx.y;
    int i = blockIdx.x * 128 + lane * 2;          // lane covers i, i+1

    int c0 = __builtin_amdgcn_readfirstlane(wv) * 32;

    float acc[18];
#pragma unroll
    for (int z = 0; z < 18; ++z) acc[z] = 0.f;

    const float* xr = x + (size_t)b * 524288 + (size_t)c0 * 4096;
    const float* wbase = wT + c0 * 32;
#pragma unroll 2
    for (int c = 0; c < 32; ++c) {
        const float* row = xr + (size_t)c * 4096;
        f32x2u v = *(const f32x2u*)(row + i);
        float left  = __shfl_up(v.y, 1);          // x[i-1] from lane-1
        float right = __shfl_down(v.x, 1);        // x[i+2] from lane+1
        if (lane == 0)  left  = (i > 0)        ? row[i - 1] : 0.f;
        if (lane == 63) right = (i + 2 < 4096) ? row[i + 2] : 0.f;
        const float* wrow = wbase + c * 32;       // wave-uniform -> s_load
#pragma unroll
        for (int ch = 0; ch < 9; ++ch) {
            float w0 = wrow[ch * 3 + 0];
            float w1 = wrow[ch * 3 + 1];
            float w2 = wrow[ch * 3 + 2];
            acc[ch * 2 + 0] += left * w0 + v.x * w1 + v.y  * w2;
            acc[ch * 2 + 1] += v.x  * w0 + v.y * w1 + right * w2;
        }
    }

    if (wv > 0) {
        float* r = &red[((wv - 1) * 64 + lane) * 18];
#pragma unroll
        for (int z = 0; z < 18; ++z) r[z] = acc[z];
    }
    __syncthreads();
    if (wv != 0) return;

#pragma unroll
    for (int z = 0; z < 18; ++z) {
        acc[z] += red[(0 * 64 + lane) * 18 + z]
                + red[(1 * 64 + lane) * 18 + z]
                + red[(2 * 64 + lane) * 18 + z];
    }

#pragma unroll
    for (int k = 0; k < 3; ++k) {
        int   av[2];
        float wav[2], wbv[2];
#pragma unroll
        for (int ii = 0; ii < 2; ++ii) {
            float offy = acc[(2 * k) * 2 + ii]     + b_off[2 * k];
            float offx = acc[(2 * k + 1) * 2 + ii] + b_off[2 * k + 1];
            offy = fminf(fmaxf(offy, -1024.f), 1024.f);
            offx = fminf(fmaxf(offx, -1024.f), 1024.f);
            float am = acc[(6 + k) * 2 + ii] + b_mod[k];
            float m  = 2.f / (1.f + expf(-am));

            float py = (float)(i + ii - 1 + k) + offy;
            float y0 = floorf(py);
            int   iy0 = (int)y0;
            float wy1 = py - y0, wy0 = 1.f - wy1;
            float x0f = floorf(offx);
            int   ix0 = (int)x0f;
            float wx1 = offx - x0f, wx0 = 1.f - wx1;

            float sx = (ix0 == 0) ? wx0 : ((ix0 == -1) ? wx1 : 0.f);
            float scal = m * sx;

            float wAv = (iy0 >= 0 && iy0 < 4096)  ? scal * wy0 : 0.f;
            float wBv = (iy0 >= -1 && iy0 < 4095) ? scal * wy1 : 0.f;

            int addr = min(max(iy0, 0), 4094);
            bool eq = (iy0 == addr);
            wav[ii] = eq ? wAv : (iy0 == -1   ? wBv : 0.f);
            wbv[ii] = eq ? wBv : (iy0 == 4095 ? wAv : 0.f);
            av[ii] = addr;
        }
        int j = (b * 3 + k) * 4096 + i;
        *(int2*)(addr2 + j)  = make_int2(av[0], av[1]);
        *(f32x2u*)(wae + j)  = (f32x2u){wav[0], wav[1]};
        *(f32x2u*)(wbe + j)  = (f32x2u){wbv[0], wbv[1]};
    }
}

// ---------- kernel 2: fused gather + MFMA GEMM, double-buffered LDS window ----------
// grid (32 i-tiles, 32 b), 256 threads = 4 waves. Block: 128 i x 128 o.
// Wave w: i-frags {2w, 2w+1}, all 8 m-frags.
__global__ __launch_bounds__(256) void k_fused(const unsigned short* __restrict__ WrA,
                                               const float* __restrict__ x,
                                               const int* __restrict__ addr2,
                                               const float* __restrict__ wae,
                                               const float* __restrict__ wbe,
                                               float* __restrict__ out) {
    __shared__ float win[2][32 * WPAD];            // 2 x 20.6 KB
    int t = threadIdx.x;
    int l = t & 63;
    int w = t >> 6;
    int b  = blockIdx.y;
    int ib = blockIdx.x;
    int q = l >> 4;
    int il = l & 15;
    int f0 = ib * 8 + 2 * w;
    int i0 = f0 * 16 + il;
    int i0t = ib * 128;
    int wsod = i0t - 16;
    if (wsod > 4096 - WIN) wsod = 4096 - WIN;
    if (wsod < 0) wsod = 0;
    const float* xb = x + (size_t)b * 524288;
    const bf16x8* Ag = (const bf16x8*)WrA;

    // constant per-thread staging geometry: chunk idx = it*256 + t
    size_t goff_[5];
    int    loff_[5];
#pragma unroll
    for (int it = 0; it < 5; ++it) {
        int idx = it * 256 + t;
        int r  = idx / 40;
        int cp = idx - r * 40;
        goff_[it] = (size_t)r * 4096 + wsod + cp * 4;
        loff_[it] = r * WPAD + cp * 4;
    }

    // hoist per-(k, i-frag) gather params + wave-uniform in-window flags
    int   a_[3][2];
    float wa_[3][2], wb_[3][2];
    bool  okw[3][2];
#pragma unroll
    for (int k = 0; k < 3; ++k) {
#pragma unroll
        for (int jj = 0; jj < 2; ++jj) {
            int j = (b * 3 + k) * 4096 + i0 + jj * 16;
            int a = addr2[j];
            a_[k][jj]  = a;
            wa_[k][jj] = wae[j];
            wb_[k][jj] = wbe[j];
            okw[k][jj] = (bool)__all(a >= wsod && a <= wsod + WIN - 2);
        }
    }

    f32x4 acc[8][2];
#pragma unroll
    for (int m = 0; m < 8; ++m) {
        acc[m][0] = (f32x4){0.f, 0.f, 0.f, 0.f};
        acc[m][1] = (f32x4){0.f, 0.f, 0.f, 0.f};
    }

    float4 stg[5];
    // prologue: stage window for cc=0 into win[0]
#pragma unroll
    for (int it = 0; it < 5; ++it)
        stg[it] = *(const float4*)(xb + goff_[it]);
#pragma unroll
    for (int it = 0; it < 5; ++it) {
        float* dst = &win[0][loff_[it]];
        dst[0] = stg[it].x; dst[1] = stg[it].y;
        dst[2] = stg[it].z; dst[3] = stg[it].w;
    }
    __syncthreads();

    for (int cc = 0; cc < 4; ++cc) {
        int pb = cc & 1;
        int cb = cc * 32;
        // issue next window's loads BEFORE compute (latency hides under MFMA)
        if (cc < 3) {
            const float* src = xb + (size_t)(cc + 1) * 131072;
#pragma unroll
            for (int it = 0; it < 5; ++it)
                stg[it] = *(const float4*)(src + goff_[it]);
        }

        const float* wbuf = win[pb];
#pragma unroll
        for (int k = 0; k < 3; ++k) {
            int s = k * 4 + cc;
            bf16x8 Bf[2];
#pragma unroll
            for (int jj = 0; jj < 2; ++jj) {
                float v[8];
                float wa = wa_[k][jj], wb = wb_[k][jj];
                if (okw[k][jj]) {
                    int pos = a_[k][jj] - wsod;
#pragma unroll
                    for (int e = 0; e < 8; ++e) {
                        const float* base = &wbuf[(q * 8 + e) * WPAD + pos];
                        v[e] = wa * base[0] + wb * base[1];   // ds_read2_b32
                    }
                } else {
                    int a = a_[k][jj];
#pragma unroll
                    for (int e = 0; e < 8; ++e) {
                        const float* row = xb + (size_t)(cb + q * 8 + e) * 4096;
                        f32x2u p2 = *(const f32x2u*)(row + a);
                        v[e] = wa * p2.x + wb * p2.y;
                    }
                }
                bf16x8 Bv;
#pragma unroll
                for (int e = 0; e < 8; ++e) Bv[e] = (short)f2bf(v[e]);
                Bf[jj] = Bv;
            }
#pragma unroll
            for (int m = 0; m < 8; ++m) {
                bf16x8 A = Ag[(m * 12 + s) * 64 + l];
                acc[m][0] = __builtin_amdgcn_mfma_f32_16x16x32_bf16(A, Bf[0], acc[m][0], 0, 0, 0);
                acc[m][1] = __builtin_amdgcn_mfma_f32_16x16x32_bf16(A, Bf[1], acc[m][1], 0, 0, 0);
            }
        }

        // write next window to the other buffer; prior barrier already ordered
        // old readers of that buffer, so only ONE barrier per phase is needed.
        if (cc < 3) {
#pragma unroll
            for (int it = 0; it < 5; ++it) {
                float* dst = &win[pb ^ 1][loff_[it]];
                dst[0] = stg[it].x; dst[1] = stg[it].y;
                dst[2] = stg[it].z; dst[3] = stg[it].w;
            }
            __syncthreads();
        }
    }

    // C layout: col = lane&15, row = (lane>>4)*4 + reg
    int col = il;
    int r0  = q * 4;
#pragma unroll
    for (int m = 0; m < 8; ++m) {
#pragma unroll
        for (int jj = 0; jj < 2; ++jj) {
            int ig = i0t + (2 * w + jj) * 16 + col;
#pragma unroll
            for (int r = 0; r < 4; ++r) {
                int o = m * 16 + r0 + r;
                out[((size_t)(b * 128 + o)) * 4096 + ig] = acc[m][jj][r];
            }
        }
    }
}

extern "C" void kernel_launch(void* const* d_in, const int* in_sizes, int n_in,
                              void* d_out, int out_size, void* d_ws, size_t ws_size,
                              hipStream_t stream) {
    const float* x     = (const float*)d_in[0];
    const float* w_off = (const float*)d_in[1];
    const float* b_off = (const float*)d_in[2];
    const float* w_mod = (const float*)d_in[3];
    const float* b_mod = (const float*)d_in[4];
    const float* w_reg = (const float*)d_in[5];
    float* out = (float*)d_out;

    char* ws = (char*)d_ws;
    unsigned short* WrA = (unsigned short*)(ws);
    float* wT    = (float*)(ws + 98304);
    int*   addr2 = (int*)  (ws + 131072);
    float* wae   = (float*)(ws + 1703936);
    float* wbe   = (float*)(ws + 3276800);

    k_wra<<<206, 256, 0, stream>>>(w_reg, w_off, w_mod, WrA, wT);
    k_prep<<<dim3(32, 32), 256, 0, stream>>>(x, wT, b_off, b_mod,
                                             addr2, wae, wbe);
    k_fused<<<dim3(32, 32), 256, 0, stream>>>(WrA, x, addr2, wae, wbe, out);
}

// Round 7
// 86.543 us; speedup vs baseline: 1.0442x; 1.0442x over previous
//
#include <hip/hip_runtime.h>
#include <hip/hip_bf16.h>
#include <math.h>

// Shapes: B=32, C=128, O=128, K=3, L=4096, W=1, PAD=1, DIL=1
// out[b,o,i] = sum_kc Wr[kc,o] * G[b,kc,i],  kc = k*128+c (K=384)
// G[b,kc,i] = wae[b,k,i]*x[b,c,addr] + wbe[b,k,i]*x[b,c,addr+1]
//
// k_fused (round-5 structure + per-k A register prefetch):
//   single LDS x-window [32c x 160i] fp32 per channel-block phase,
//   stage -> barrier -> { per k: A-frags->VGPR, B-build via ds_read2, MFMA }.
//   Staging loads fully drained at the barrier so in-compute A-loads'
//   vmcnt waits never drain HBM staging traffic (round-6 lesson).
//
// ws layout (bytes):
//   WrA @ 0       : bf16 A-frags, 8 m x 12 s x 64 lanes x 16B = 98304
//   wT  @ 98304   : float[128*32] transposed conv weights, wT[c*32+ch*3+tap]
//   addr2 @ 131072: int[32*3*4096]
//   wae @ 1703936 : float[32*3*4096]
//   wbe @ 3276800 : float[32*3*4096]

typedef __attribute__((ext_vector_type(8))) short bf16x8;
typedef __attribute__((ext_vector_type(4))) float f32x4;
typedef float f32x2u __attribute__((ext_vector_type(2), aligned(4)));

#define WIN 160
#define WPAD 161

static __device__ inline unsigned short f2bf(float f) {
    __hip_bfloat16 h = __float2bfloat16(f);
    union { __hip_bfloat16 b; unsigned short u; } cv;
    cv.b = h;
    return cv.u;
}

// ---------- kernel 0: pack WrA (A-frags) + wT (transposed conv weights) ----------
// A-frag (m,s), lane l, elem e:  A[o = m*16+(l&15)][kc = s*32+(l>>4)*8+e]
__global__ __launch_bounds__(256) void k_wra(const float* __restrict__ w_reg,
                                             const float* __restrict__ w_off,
                                             const float* __restrict__ w_mod,
                                             unsigned short* __restrict__ WrA,
                                             float* __restrict__ wT) {
    int t = blockIdx.x * 256 + threadIdx.x;
    if (t < 8 * 12 * 64 * 8) {
        int e  = t & 7;
        int l  = (t >> 3) & 63;
        int ms = t >> 9;              // m*12 + s
        int m  = ms / 12;
        int s  = ms - m * 12;
        int o  = m * 16 + (l & 15);
        int kc = s * 32 + ((l >> 4) & 3) * 8 + e;
        int tap = kc >> 7;
        int c   = kc & 127;
        WrA[t] = f2bf(w_reg[(o * 128 + c) * 3 + tap]);
    } else if (t < 8 * 12 * 64 * 8 + 128 * 27) {
        int u = t - 8 * 12 * 64 * 8;
        int c = u / 27, r = u - c * 27;
        int ch = r / 3, tap = r - ch * 3;
        wT[c * 32 + r] = (ch < 6) ? w_off[(ch * 128 + c) * 3 + tap]
                                  : w_mod[((ch - 6) * 128 + c) * 3 + tap];
    }
}

// ---------- kernel 1: offset/mask conv, 8 waves x 16 channels ----------
// grid (32, 32): 128-i tiles, lane owns i,i+1. Wave wv sums c in [16wv,16wv+16).
__global__ __launch_bounds__(512) void k_prep(const float* __restrict__ x,
                                              const float* __restrict__ wT,
                                              const float* __restrict__ b_off,
                                              const float* __restrict__ b_mod,
                                              int* __restrict__ addr2,
                                              float* __restrict__ wae,
                                              float* __restrict__ wbe) {
    __shared__ float red[7 * 64 * 19];            // 34 KB, stride 19 (odd)
    int t = threadIdx.x;
    int lane = t & 63;
    int wv = t >> 6;                              // 0..7
    int b = blockIdx.y;
    int i = blockIdx.x * 128 + lane * 2;          // lane covers i, i+1

    int c0 = __builtin_amdgcn_readfirstlane(wv) * 16;

    float acc[18];
#pragma unroll
    for (int z = 0; z < 18; ++z) acc[z] = 0.f;

    const float* xr = x + (size_t)b * 524288 + (size_t)c0 * 4096;
    const float* wbase = wT + c0 * 32;
#pragma unroll 2
    for (int c = 0; c < 16; ++c) {
        const float* row = xr + (size_t)c * 4096;
        f32x2u v = *(const f32x2u*)(row + i);
        float lm = row[max(i - 1, 0)];            // unconditional, no divergence
        float rp = row[min(i + 2, 4095)];
        float left  = (i > 0)        ? lm : 0.f;
        float right = (i + 2 < 4096) ? rp : 0.f;
        const float* wrow = wbase + c * 32;       // wave-uniform -> s_load
#pragma unroll
        for (int ch = 0; ch < 9; ++ch) {
            float w0 = wrow[ch * 3 + 0];
            float w1 = wrow[ch * 3 + 1];
            float w2 = wrow[ch * 3 + 2];
            acc[ch * 2 + 0] += left * w0 + v.x * w1 + v.y  * w2;
            acc[ch * 2 + 1] += v.x  * w0 + v.y * w1 + right * w2;
        }
    }

    if (wv > 0) {
        float* r = &red[((wv - 1) * 64 + lane) * 19];
#pragma unroll
        for (int z = 0; z < 18; ++z) r[z] = acc[z];
    }
    __syncthreads();
    if (wv != 0) return;

#pragma unroll
    for (int p = 0; p < 7; ++p) {
        const float* r = &red[(p * 64 + lane) * 19];
#pragma unroll
        for (int z = 0; z < 18; ++z) acc[z] += r[z];
    }

#pragma unroll
    for (int k = 0; k < 3; ++k) {
        int   av[2];
        float wav[2], wbv[2];
#pragma unroll
        for (int ii = 0; ii < 2; ++ii) {
            float offy = acc[(2 * k) * 2 + ii]     + b_off[2 * k];
            float offx = acc[(2 * k + 1) * 2 + ii] + b_off[2 * k + 1];
            offy = fminf(fmaxf(offy, -1024.f), 1024.f);
            offx = fminf(fmaxf(offx, -1024.f), 1024.f);
            float am = acc[(6 + k) * 2 + ii] + b_mod[k];
            float m  = 2.f / (1.f + expf(-am));

            float py = (float)(i + ii - 1 + k) + offy;
            float y0 = floorf(py);
            int   iy0 = (int)y0;
            float wy1 = py - y0, wy0 = 1.f - wy1;
            float x0f = floorf(offx);
            int   ix0 = (int)x0f;
            float wx1 = offx - x0f, wx0 = 1.f - wx1;

            float sx = (ix0 == 0) ? wx0 : ((ix0 == -1) ? wx1 : 0.f);
            float scal = m * sx;

            float wAv = (iy0 >= 0 && iy0 < 4096)  ? scal * wy0 : 0.f;
            float wBv = (iy0 >= -1 && iy0 < 4095) ? scal * wy1 : 0.f;

            int addr = min(max(iy0, 0), 4094);
            bool eq = (iy0 == addr);
            wav[ii] = eq ? wAv : (iy0 == -1   ? wBv : 0.f);
            wbv[ii] = eq ? wBv : (iy0 == 4095 ? wAv : 0.f);
            av[ii] = addr;
        }
        int j = (b * 3 + k) * 4096 + i;
        *(int2*)(addr2 + j)  = make_int2(av[0], av[1]);
        *(f32x2u*)(wae + j)  = (f32x2u){wav[0], wav[1]};
        *(f32x2u*)(wbe + j)  = (f32x2u){wbv[0], wbv[1]};
    }
}

// ---------- kernel 2: fused gather + MFMA GEMM, LDS x-window ----------
// grid (32 i-tiles, 32 b), 256 threads = 4 waves. Block: 128 i x 128 o.
// Wave w: i-frags {2w, 2w+1}, all 8 m-frags. Per-k A-frag register prefetch.
__global__ __launch_bounds__(256, 3) void k_fused(const unsigned short* __restrict__ WrA,
                                                  const float* __restrict__ x,
                                                  const int* __restrict__ addr2,
                                                  const float* __restrict__ wae,
                                                  const float* __restrict__ wbe,
                                                  float* __restrict__ out) {
    __shared__ float win[32 * WPAD];               // 20.6 KB
    int t = threadIdx.x;
    int l = t & 63;
    int w = t >> 6;
    int b  = blockIdx.y;
    int ib = blockIdx.x;
    int q = l >> 4;
    int il = l & 15;
    int f0 = ib * 8 + 2 * w;
    int i0 = f0 * 16 + il;
    int i0t = ib * 128;
    int wsod = i0t - 16;
    if (wsod > 4096 - WIN) wsod = 4096 - WIN;
    if (wsod < 0) wsod = 0;
    const float* xb = x + (size_t)b * 524288;
    const bf16x8* Ag = (const bf16x8*)WrA;

    // hoist per-(k, i-frag) gather params + wave-uniform in-window flags
    int   a_[3][2];
    float wa_[3][2], wb_[3][2];
    bool  okw[3][2];
#pragma unroll
    for (int k = 0; k < 3; ++k) {
#pragma unroll
        for (int jj = 0; jj < 2; ++jj) {
            int j = (b * 3 + k) * 4096 + i0 + jj * 16;
            int a = addr2[j];
            a_[k][jj]  = a;
            wa_[k][jj] = wae[j];
            wb_[k][jj] = wbe[j];
            okw[k][jj] = (bool)__all(a >= wsod && a <= wsod + WIN - 2);
        }
    }

    f32x4 acc[8][2];
#pragma unroll
    for (int m = 0; m < 8; ++m) {
        acc[m][0] = (f32x4){0.f, 0.f, 0.f, 0.f};
        acc[m][1] = (f32x4){0.f, 0.f, 0.f, 0.f};
    }

    for (int cc = 0; cc < 4; ++cc) {
        int cb = cc * 32;
        __syncthreads();                            // window free to overwrite
        // stage window: 32 rows x 160 fp32, coalesced dwordx4; fully drained
        // at the barrier below (keeps vmcnt clean for in-compute A loads)
#pragma unroll
        for (int it = 0; it < 5; ++it) {
            int idx = it * 256 + t;                 // 0..1279 x4-chunks
            int r  = idx / 40;
            int cp = idx - r * 40;
            float4 v = *(const float4*)(xb + (size_t)(cb + r) * 4096 + wsod + cp * 4);
            float* dst = &win[r * WPAD + cp * 4];
            dst[0] = v.x; dst[1] = v.y; dst[2] = v.z; dst[3] = v.w;
        }
        __syncthreads();

#pragma unroll
        for (int k = 0; k < 3; ++k) {
            int s = k * 4 + cc;
            // A-frag register prefetch: issue before B-build so L2 latency
            // hides under the ds_read2/cvt work
            bf16x8 Areg[8];
#pragma unroll
            for (int m = 0; m < 8; ++m)
                Areg[m] = Ag[(m * 12 + s) * 64 + l];

            bf16x8 Bf[2];
#pragma unroll
            for (int jj = 0; jj < 2; ++jj) {
                float v[8];
                float wa = wa_[k][jj], wb = wb_[k][jj];
                if (okw[k][jj]) {
                    int pos = a_[k][jj] - wsod;
#pragma unroll
                    for (int e = 0; e < 8; ++e) {
                        const float* base = &win[(q * 8 + e) * WPAD + pos];
                        v[e] = wa * base[0] + wb * base[1];   // ds_read2_b32
                    }
                } else {
                    int a = a_[k][jj];
#pragma unroll
                    for (int e = 0; e < 8; ++e) {
                        const float* row = xb + (size_t)(cb + q * 8 + e) * 4096;
                        f32x2u p2 = *(const f32x2u*)(row + a);
                        v[e] = wa * p2.x + wb * p2.y;
                    }
                }
                bf16x8 Bv;
#pragma unroll
                for (int e = 0; e < 8; ++e) Bv[e] = (short)f2bf(v[e]);
                Bf[jj] = Bv;
            }
#pragma unroll
            for (int m = 0; m < 8; ++m) {
                acc[m][0] = __builtin_amdgcn_mfma_f32_16x16x32_bf16(Areg[m], Bf[0], acc[m][0], 0, 0, 0);
                acc[m][1] = __builtin_amdgcn_mfma_f32_16x16x32_bf16(Areg[m], Bf[1], acc[m][1], 0, 0, 0);
            }
        }
    }

    // C layout: col = lane&15, row = (lane>>4)*4 + reg
    int col = il;
    int r0  = q * 4;
#pragma unroll
    for (int m = 0; m < 8; ++m) {
#pragma unroll
        for (int jj = 0; jj < 2; ++jj) {
            int ig = i0t + (2 * w + jj) * 16 + col;
#pragma unroll
            for (int r = 0; r < 4; ++r) {
                int o = m * 16 + r0 + r;
                out[((size_t)(b * 128 + o)) * 4096 + ig] = acc[m][jj][r];
            }
        }
    }
}

extern "C" void kernel_launch(void* const* d_in, const int* in_sizes, int n_in,
                              void* d_out, int out_size, void* d_ws, size_t ws_size,
                              hipStream_t stream) {
    const float* x     = (const float*)d_in[0];
    const float* w_off = (const float*)d_in[1];
    const float* b_off = (const float*)d_in[2];
    const float* w_mod = (const float*)d_in[3];
    const float* b_mod = (const float*)d_in[4];
    const float* w_reg = (const float*)d_in[5];
    float* out = (float*)d_out;

    char* ws = (char*)d_ws;
    unsigned short* WrA = (unsigned short*)(ws);
    float* wT    = (float*)(ws + 98304);
    int*   addr2 = (int*)  (ws + 131072);
    float* wae   = (float*)(ws + 1703936);
    float* wbe   = (float*)(ws + 3276800);

    k_wra<<<206, 256, 0, stream>>>(w_reg, w_off, w_mod, WrA, wT);
    k_prep<<<dim3(32, 32), 512, 0, stream>>>(x, wT, b_off, b_mod,
                                             addr2, wae, wbe);
    k_fused<<<dim3(32, 32), 256, 0, stream>>>(WrA, x, addr2, wae, wbe, out);
}

// Round 8
// 77.967 us; speedup vs baseline: 1.1591x; 1.1100x over previous
//
#include <hip/hip_runtime.h>
#include <hip/hip_bf16.h>
#include <math.h>

// Shapes: B=32, C=128, O=128, K=3, L=4096, W=1, PAD=1, DIL=1
// out[b,o,i] = sum_kc Wr[kc,o] * G[b,kc,i],  kc = k*128+c (K=384)
// G[b,kc,i] = wae[b,k,i]*x[b,c,addr] + wbe[b,k,i]*x[b,c,addr+1]
//
// k_fused: 512 threads = 8 waves, each wave owns ONE 16-i frag x all 8 o-frags
// (acc = 32 VGPR -> ~4 waves/SIMD occupancy, vs 2 at acc=64 in round 5).
// Single LDS x-window [32c x 160i] per channel-block phase; stage -> barrier ->
// compute (ds_read2 interp -> bf16 B-frag -> MFMA with inline L2 A-loads).
//
// ws layout (bytes):
//   WrA @ 0       : bf16 A-frags, 8 m x 12 s x 64 lanes x 16B = 98304
//   wT  @ 98304   : float[128*32] transposed conv weights, wT[c*32+ch*3+tap]
//   addr2 @ 131072: int[32*3*4096]
//   wae @ 1703936 : float[32*3*4096]
//   wbe @ 3276800 : float[32*3*4096]

typedef __attribute__((ext_vector_type(8))) short bf16x8;
typedef __attribute__((ext_vector_type(4))) float f32x4;
typedef float f32x2u __attribute__((ext_vector_type(2), aligned(4)));

#define WIN 160
#define WPAD 161

static __device__ inline unsigned short f2bf(float f) {
    __hip_bfloat16 h = __float2bfloat16(f);
    union { __hip_bfloat16 b; unsigned short u; } cv;
    cv.b = h;
    return cv.u;
}

// ---------- kernel 0: pack WrA (A-frags) + wT (transposed conv weights) ----------
// A-frag (m,s), lane l, elem e:  A[o = m*16+(l&15)][kc = s*32+(l>>4)*8+e]
__global__ __launch_bounds__(256) void k_wra(const float* __restrict__ w_reg,
                                             const float* __restrict__ w_off,
                                             const float* __restrict__ w_mod,
                                             unsigned short* __restrict__ WrA,
                                             float* __restrict__ wT) {
    int t = blockIdx.x * 256 + threadIdx.x;
    if (t < 8 * 12 * 64 * 8) {
        int e  = t & 7;
        int l  = (t >> 3) & 63;
        int ms = t >> 9;              // m*12 + s
        int m  = ms / 12;
        int s  = ms - m * 12;
        int o  = m * 16 + (l & 15);
        int kc = s * 32 + ((l >> 4) & 3) * 8 + e;
        int tap = kc >> 7;
        int c   = kc & 127;
        WrA[t] = f2bf(w_reg[(o * 128 + c) * 3 + tap]);
    } else if (t < 8 * 12 * 64 * 8 + 128 * 27) {
        int u = t - 8 * 12 * 64 * 8;
        int c = u / 27, r = u - c * 27;
        int ch = r / 3, tap = r - ch * 3;
        wT[c * 32 + r] = (ch < 6) ? w_off[(ch * 128 + c) * 3 + tap]
                                  : w_mod[((ch - 6) * 128 + c) * 3 + tap];
    }
}

// ---------- kernel 1: offset/mask conv, 8 waves x 16 channels ----------
// grid (32, 32): 128-i tiles, lane owns i,i+1. Wave wv sums c in [16wv,16wv+16).
__global__ __launch_bounds__(512) void k_prep(const float* __restrict__ x,
                                              const float* __restrict__ wT,
                                              const float* __restrict__ b_off,
                                              const float* __restrict__ b_mod,
                                              int* __restrict__ addr2,
                                              float* __restrict__ wae,
                                              float* __restrict__ wbe) {
    __shared__ float red[7 * 64 * 19];            // 34 KB, stride 19 (odd)
    int t = threadIdx.x;
    int lane = t & 63;
    int wv = t >> 6;                              // 0..7
    int b = blockIdx.y;
    int i = blockIdx.x * 128 + lane * 2;          // lane covers i, i+1

    int c0 = __builtin_amdgcn_readfirstlane(wv) * 16;

    float acc[18];
#pragma unroll
    for (int z = 0; z < 18; ++z) acc[z] = 0.f;

    const float* xr = x + (size_t)b * 524288 + (size_t)c0 * 4096;
    const float* wbase = wT + c0 * 32;
#pragma unroll 2
    for (int c = 0; c < 16; ++c) {
        const float* row = xr + (size_t)c * 4096;
        f32x2u v = *(const f32x2u*)(row + i);
        float lm = row[max(i - 1, 0)];            // unconditional, no divergence
        float rp = row[min(i + 2, 4095)];
        float left  = (i > 0)        ? lm : 0.f;
        float right = (i + 2 < 4096) ? rp : 0.f;
        const float* wrow = wbase + c * 32;       // wave-uniform -> s_load
#pragma unroll
        for (int ch = 0; ch < 9; ++ch) {
            float w0 = wrow[ch * 3 + 0];
            float w1 = wrow[ch * 3 + 1];
            float w2 = wrow[ch * 3 + 2];
            acc[ch * 2 + 0] += left * w0 + v.x * w1 + v.y  * w2;
            acc[ch * 2 + 1] += v.x  * w0 + v.y * w1 + right * w2;
        }
    }

    if (wv > 0) {
        float* r = &red[((wv - 1) * 64 + lane) * 19];
#pragma unroll
        for (int z = 0; z < 18; ++z) r[z] = acc[z];
    }
    __syncthreads();
    if (wv != 0) return;

#pragma unroll
    for (int p = 0; p < 7; ++p) {
        const float* r = &red[(p * 64 + lane) * 19];
#pragma unroll
        for (int z = 0; z < 18; ++z) acc[z] += r[z];
    }

#pragma unroll
    for (int k = 0; k < 3; ++k) {
        int   av[2];
        float wav[2], wbv[2];
#pragma unroll
        for (int ii = 0; ii < 2; ++ii) {
            float offy = acc[(2 * k) * 2 + ii]     + b_off[2 * k];
            float offx = acc[(2 * k + 1) * 2 + ii] + b_off[2 * k + 1];
            offy = fminf(fmaxf(offy, -1024.f), 1024.f);
            offx = fminf(fmaxf(offx, -1024.f), 1024.f);
            float am = acc[(6 + k) * 2 + ii] + b_mod[k];
            float m  = 2.f / (1.f + expf(-am));

            float py = (float)(i + ii - 1 + k) + offy;
            float y0 = floorf(py);
            int   iy0 = (int)y0;
            float wy1 = py - y0, wy0 = 1.f - wy1;
            float x0f = floorf(offx);
            int   ix0 = (int)x0f;
            float wx1 = offx - x0f, wx0 = 1.f - wx1;

            float sx = (ix0 == 0) ? wx0 : ((ix0 == -1) ? wx1 : 0.f);
            float scal = m * sx;

            float wAv = (iy0 >= 0 && iy0 < 4096)  ? scal * wy0 : 0.f;
            float wBv = (iy0 >= -1 && iy0 < 4095) ? scal * wy1 : 0.f;

            int addr = min(max(iy0, 0), 4094);
            bool eq = (iy0 == addr);
            wav[ii] = eq ? wAv : (iy0 == -1   ? wBv : 0.f);
            wbv[ii] = eq ? wBv : (iy0 == 4095 ? wAv : 0.f);
            av[ii] = addr;
        }
        int j = (b * 3 + k) * 4096 + i;
        *(int2*)(addr2 + j)  = make_int2(av[0], av[1]);
        *(f32x2u*)(wae + j)  = (f32x2u){wav[0], wav[1]};
        *(f32x2u*)(wbe + j)  = (f32x2u){wbv[0], wbv[1]};
    }
}

// ---------- kernel 2: fused gather + MFMA GEMM, 8 waves x 1 i-frag ----------
// grid (32 i-tiles, 32 b), 512 threads = 8 waves. Block: 128 i x 128 o.
// Wave w: i-frag ib*8+w, all 8 m-frags (acc = 32 VGPR).
__global__ __launch_bounds__(512) void k_fused(const unsigned short* __restrict__ WrA,
                                               const float* __restrict__ x,
                                               const int* __restrict__ addr2,
                                               const float* __restrict__ wae,
                                               const float* __restrict__ wbe,
                                               float* __restrict__ out) {
    __shared__ float win[32 * WPAD];               // 20.6 KB
    int t = threadIdx.x;
    int l = t & 63;
    int w = t >> 6;                                // 0..7
    int b  = blockIdx.y;
    int ib = blockIdx.x;
    int q = l >> 4;
    int il = l & 15;
    int f0 = ib * 8 + w;                           // this wave's i-frag
    int i0 = f0 * 16 + il;
    int i0t = ib * 128;
    int wsod = i0t - 16;
    if (wsod > 4096 - WIN) wsod = 4096 - WIN;
    if (wsod < 0) wsod = 0;
    const float* xb = x + (size_t)b * 524288;
    const bf16x8* Ag = (const bf16x8*)WrA;

    // hoist per-k gather params + wave-uniform in-window flags
    int   a_[3];
    float wa_[3], wb_[3];
    bool  okw[3];
#pragma unroll
    for (int k = 0; k < 3; ++k) {
        int j = (b * 3 + k) * 4096 + i0;
        int a = addr2[j];
        a_[k]  = a;
        wa_[k] = wae[j];
        wb_[k] = wbe[j];
        okw[k] = (bool)__all(a >= wsod && a <= wsod + WIN - 2);
    }

    f32x4 acc[8];
#pragma unroll
    for (int m = 0; m < 8; ++m) acc[m] = (f32x4){0.f, 0.f, 0.f, 0.f};

    for (int cc = 0; cc < 4; ++cc) {
        int cb = cc * 32;
        __syncthreads();                            // window free to overwrite
        // stage window: 32 rows x 160 fp32 = 1280 float4-chunks over 512 threads
#pragma unroll
        for (int it = 0; it < 3; ++it) {
            int idx = it * 512 + t;
            if (idx < 1280) {
                int r  = idx / 40;
                int cp = idx - r * 40;
                float4 v = *(const float4*)(xb + (size_t)(cb + r) * 4096 + wsod + cp * 4);
                float* dst = &win[r * WPAD + cp * 4];
                dst[0] = v.x; dst[1] = v.y; dst[2] = v.z; dst[3] = v.w;
            }
        }
        __syncthreads();

#pragma unroll
        for (int k = 0; k < 3; ++k) {
            int s = k * 4 + cc;
            float v[8];
            float wa = wa_[k], wb = wb_[k];
            if (okw[k]) {
                int pos = a_[k] - wsod;
#pragma unroll
                for (int e = 0; e < 8; ++e) {
                    const float* base = &win[(q * 8 + e) * WPAD + pos];
                    v[e] = wa * base[0] + wb * base[1];   // ds_read2_b32
                }
            } else {
                int a = a_[k];
#pragma unroll
                for (int e = 0; e < 8; ++e) {
                    const float* row = xb + (size_t)(cb + q * 8 + e) * 4096;
                    f32x2u p2 = *(const f32x2u*)(row + a);
                    v[e] = wa * p2.x + wb * p2.y;
                }
            }
            bf16x8 Bv;
#pragma unroll
            for (int e = 0; e < 8; ++e) Bv[e] = (short)f2bf(v[e]);
#pragma unroll
            for (int m = 0; m < 8; ++m) {
                bf16x8 A = Ag[(m * 12 + s) * 64 + l];
                acc[m] = __builtin_amdgcn_mfma_f32_16x16x32_bf16(A, Bv, acc[m], 0, 0, 0);
            }
        }
    }

    // C layout: col = lane&15, row = (lane>>4)*4 + reg
    int r0 = q * 4;
#pragma unroll
    for (int m = 0; m < 8; ++m) {
#pragma unroll
        for (int r = 0; r < 4; ++r) {
            int o = m * 16 + r0 + r;
            out[((size_t)(b * 128 + o)) * 4096 + i0] = acc[m][r];
        }
    }
}

extern "C" void kernel_launch(void* const* d_in, const int* in_sizes, int n_in,
                              void* d_out, int out_size, void* d_ws, size_t ws_size,
                              hipStream_t stream) {
    const float* x     = (const float*)d_in[0];
    const float* w_off = (const float*)d_in[1];
    const float* b_off = (const float*)d_in[2];
    const float* w_mod = (const float*)d_in[3];
    const float* b_mod = (const float*)d_in[4];
    const float* w_reg = (const float*)d_in[5];
    float* out = (float*)d_out;

    char* ws = (char*)d_ws;
    unsigned short* WrA = (unsigned short*)(ws);
    float* wT    = (float*)(ws + 98304);
    int*   addr2 = (int*)  (ws + 131072);
    float* wae   = (float*)(ws + 1703936);
    float* wbe   = (float*)(ws + 3276800);

    k_wra<<<206, 256, 0, stream>>>(w_reg, w_off, w_mod, WrA, wT);
    k_prep<<<dim3(32, 32), 512, 0, stream>>>(x, wT, b_off, b_mod,
                                             addr2, wae, wbe);
    k_fused<<<dim3(32, 32), 512, 0, stream>>>(WrA, x, addr2, wae, wbe, out);
}

// Round 9
// 66.649 us; speedup vs baseline: 1.3559x; 1.1698x over previous
//
#include <hip/hip_runtime.h>
#include <hip/hip_bf16.h>
#include <math.h>

// Shapes: B=32, C=128, O=128, K=3, L=4096, W=1, PAD=1, DIL=1
// out[b,o,i] = sum_kc Wr[kc,o] * G[b,kc,i],  kc = k*128+c (K=384)
// G[b,kc,i] = wae[b,k,i]*x[b,c,addr] + wbe[b,k,i]*x[b,c,addr+1]
//
// k_fused role-swap (round-9): wave w owns ONE m-frag, A-frags in REGISTERS
// (12 VMEM loads/wave/kernel vs 96 in round 8 -> TA pipe relieved).
// B-frags produced once per (i-frag,k) into LDS, shared by all 8 waves.
// Per phase: producer(interp->B LDS) -> sync -> consumer(MFMA, no VMEM,
// next window's loads in flight underneath: T14, vmcnt-safe) -> win write -> sync.
//
// ws layout (bytes):
//   WrA @ 0       : bf16 A-frags, 8 m x 12 s x 64 lanes x 16B = 98304
//   wT  @ 98304   : float[128*32] transposed conv weights, wT[c*32+ch*3+tap]
//   addr2 @ 131072: int[32*3*4096]
//   wae @ 1703936 : float[32*3*4096]
//   wbe @ 3276800 : float[32*3*4096]

typedef __attribute__((ext_vector_type(8))) short bf16x8;
typedef __attribute__((ext_vector_type(4))) float f32x4;
typedef float f32x2u __attribute__((ext_vector_type(2), aligned(4)));

#define WIN 160
#define WPAD 161

static __device__ inline unsigned short f2bf(float f) {
    __hip_bfloat16 h = __float2bfloat16(f);
    union { __hip_bfloat16 b; unsigned short u; } cv;
    cv.b = h;
    return cv.u;
}

// ---------- kernel 0: pack WrA (A-frags) + wT (transposed conv weights) ----------
// A-frag (m,s), lane l, elem e:  A[o = m*16+(l&15)][kc = s*32+(l>>4)*8+e]
__global__ __launch_bounds__(256) void k_wra(const float* __restrict__ w_reg,
                                             const float* __restrict__ w_off,
                                             const float* __restrict__ w_mod,
                                             unsigned short* __restrict__ WrA,
                                             float* __restrict__ wT) {
    int t = blockIdx.x * 256 + threadIdx.x;
    if (t < 8 * 12 * 64 * 8) {
        int e  = t & 7;
        int l  = (t >> 3) & 63;
        int ms = t >> 9;              // m*12 + s
        int m  = ms / 12;
        int s  = ms - m * 12;
        int o  = m * 16 + (l & 15);
        int kc = s * 32 + ((l >> 4) & 3) * 8 + e;
        int tap = kc >> 7;
        int c   = kc & 127;
        WrA[t] = f2bf(w_reg[(o * 128 + c) * 3 + tap]);
    } else if (t < 8 * 12 * 64 * 8 + 128 * 27) {
        int u = t - 8 * 12 * 64 * 8;
        int c = u / 27, r = u - c * 27;
        int ch = r / 3, tap = r - ch * 3;
        wT[c * 32 + r] = (ch < 6) ? w_off[(ch * 128 + c) * 3 + tap]
                                  : w_mod[((ch - 6) * 128 + c) * 3 + tap];
    }
}

// ---------- kernel 1: offset/mask conv, 8 waves x 16 channels ----------
// grid (32, 32): 128-i tiles, lane owns i,i+1. Wave wv sums c in [16wv,16wv+16).
__global__ __launch_bounds__(512) void k_prep(const float* __restrict__ x,
                                              const float* __restrict__ wT,
                                              const float* __restrict__ b_off,
                                              const float* __restrict__ b_mod,
                                              int* __restrict__ addr2,
                                              float* __restrict__ wae,
                                              float* __restrict__ wbe) {
    __shared__ float red[7 * 64 * 19];            // 34 KB, stride 19 (odd)
    int t = threadIdx.x;
    int lane = t & 63;
    int wv = t >> 6;                              // 0..7
    int b = blockIdx.y;
    int i = blockIdx.x * 128 + lane * 2;          // lane covers i, i+1

    int c0 = __builtin_amdgcn_readfirstlane(wv) * 16;

    float acc[18];
#pragma unroll
    for (int z = 0; z < 18; ++z) acc[z] = 0.f;

    const float* xr = x + (size_t)b * 524288 + (size_t)c0 * 4096;
    const float* wbase = wT + c0 * 32;
#pragma unroll 2
    for (int c = 0; c < 16; ++c) {
        const float* row = xr + (size_t)c * 4096;
        f32x2u v = *(const f32x2u*)(row + i);
        float lm = row[max(i - 1, 0)];            // unconditional, no divergence
        float rp = row[min(i + 2, 4095)];
        float left  = (i > 0)        ? lm : 0.f;
        float right = (i + 2 < 4096) ? rp : 0.f;
        const float* wrow = wbase + c * 32;       // wave-uniform -> s_load
#pragma unroll
        for (int ch = 0; ch < 9; ++ch) {
            float w0 = wrow[ch * 3 + 0];
            float w1 = wrow[ch * 3 + 1];
            float w2 = wrow[ch * 3 + 2];
            acc[ch * 2 + 0] += left * w0 + v.x * w1 + v.y  * w2;
            acc[ch * 2 + 1] += v.x  * w0 + v.y * w1 + right * w2;
        }
    }

    if (wv > 0) {
        float* r = &red[((wv - 1) * 64 + lane) * 19];
#pragma unroll
        for (int z = 0; z < 18; ++z) r[z] = acc[z];
    }
    __syncthreads();
    if (wv != 0) return;

#pragma unroll
    for (int p = 0; p < 7; ++p) {
        const float* r = &red[(p * 64 + lane) * 19];
#pragma unroll
        for (int z = 0; z < 18; ++z) acc[z] += r[z];
    }

#pragma unroll
    for (int k = 0; k < 3; ++k) {
        int   av[2];
        float wav[2], wbv[2];
#pragma unroll
        for (int ii = 0; ii < 2; ++ii) {
            float offy = acc[(2 * k) * 2 + ii]     + b_off[2 * k];
            float offx = acc[(2 * k + 1) * 2 + ii] + b_off[2 * k + 1];
            offy = fminf(fmaxf(offy, -1024.f), 1024.f);
            offx = fminf(fmaxf(offx, -1024.f), 1024.f);
            float am = acc[(6 + k) * 2 + ii] + b_mod[k];
            float m  = 2.f / (1.f + expf(-am));

            float py = (float)(i + ii - 1 + k) + offy;
            float y0 = floorf(py);
            int   iy0 = (int)y0;
            float wy1 = py - y0, wy0 = 1.f - wy1;
            float x0f = floorf(offx);
            int   ix0 = (int)x0f;
            float wx1 = offx - x0f, wx0 = 1.f - wx1;

            float sx = (ix0 == 0) ? wx0 : ((ix0 == -1) ? wx1 : 0.f);
            float scal = m * sx;

            float wAv = (iy0 >= 0 && iy0 < 4096)  ? scal * wy0 : 0.f;
            float wBv = (iy0 >= -1 && iy0 < 4095) ? scal * wy1 : 0.f;

            int addr = min(max(iy0, 0), 4094);
            bool eq = (iy0 == addr);
            wav[ii] = eq ? wAv : (iy0 == -1   ? wBv : 0.f);
            wbv[ii] = eq ? wBv : (iy0 == 4095 ? wAv : 0.f);
            av[ii] = addr;
        }
        int j = (b * 3 + k) * 4096 + i;
        *(int2*)(addr2 + j)  = make_int2(av[0], av[1]);
        *(f32x2u*)(wae + j)  = (f32x2u){wav[0], wav[1]};
        *(f32x2u*)(wbe + j)  = (f32x2u){wbv[0], wbv[1]};
    }
}

// ---------- kernel 2: fused gather + MFMA GEMM, producer/consumer role-swap ----------
// grid (32 i-tiles, 32 b), 512 threads = 8 waves. Block: 128 i x 128 o.
// Wave w: produces B-frags for i-frag w; consumes as m-frag w (A in regs).
__global__ __launch_bounds__(512) void k_fused(const unsigned short* __restrict__ WrA,
                                               const float* __restrict__ x,
                                               const int* __restrict__ addr2,
                                               const float* __restrict__ wae,
                                               const float* __restrict__ wbe,
                                               float* __restrict__ out) {
    __shared__ float win[32 * WPAD];               // 20.6 KB
    __shared__ short Bl[2][8][3][512];             // 2 x 24 KB B-frags
    int t = threadIdx.x;
    int l = t & 63;
    int w = t >> 6;                                // 0..7 = i-frag (prod) / m-frag (cons)
    int b  = blockIdx.y;
    int ib = blockIdx.x;
    int q = l >> 4;
    int il = l & 15;
    int i0t = ib * 128;
    int i0p = i0t + w * 16 + il;                   // producer's i
    int wsod = i0t - 16;
    if (wsod > 4096 - WIN) wsod = 4096 - WIN;
    if (wsod < 0) wsod = 0;
    const float* xb = x + (size_t)b * 524288;
    const bf16x8* Ag = (const bf16x8*)WrA;

    // producer gather params (own i-frag) + wave-uniform in-window flags
    int   a_[3];
    float wa_[3], wb_[3];
    bool  okw[3];
#pragma unroll
    for (int k = 0; k < 3; ++k) {
        int j = (b * 3 + k) * 4096 + i0p;
        int a = addr2[j];
        a_[k]  = a;
        wa_[k] = wae[j];
        wb_[k] = wbe[j];
        okw[k] = (bool)__all(a >= wsod && a <= wsod + WIN - 2);
    }

    f32x4 acc[8];
#pragma unroll
    for (int f = 0; f < 8; ++f) acc[f] = (f32x4){0.f, 0.f, 0.f, 0.f};

    // prologue: stage window for cc=0
#pragma unroll
    for (int it = 0; it < 3; ++it) {
        int idx = it * 512 + t;
        if (idx < 1280) {
            int r  = idx / 40;
            int cp = idx - r * 40;
            float4 v = *(const float4*)(xb + (size_t)r * 4096 + wsod + cp * 4);
            float* dst = &win[r * WPAD + cp * 4];
            dst[0] = v.x; dst[1] = v.y; dst[2] = v.z; dst[3] = v.w;
        }
    }
    __syncthreads();

    for (int cc = 0; cc < 4; ++cc) {
        int p  = cc & 1;
        int cb = cc * 32;

        // --- producer: A-frags for this phase + interp own i-frag -> B LDS ---
        bf16x8 Areg[3];
#pragma unroll
        for (int k = 0; k < 3; ++k)
            Areg[k] = Ag[(w * 12 + k * 4 + cc) * 64 + l];

#pragma unroll
        for (int k = 0; k < 3; ++k) {
            float v[8];
            float wa = wa_[k], wb = wb_[k];
            if (okw[k]) {
                int pos = a_[k] - wsod;
#pragma unroll
                for (int e = 0; e < 8; ++e) {
                    const float* base = &win[(q * 8 + e) * WPAD + pos];
                    v[e] = wa * base[0] + wb * base[1];   // ds_read2_b32
                }
            } else {
                int a = a_[k];
#pragma unroll
                for (int e = 0; e < 8; ++e) {
                    const float* row = xb + (size_t)(cb + q * 8 + e) * 4096;
                    f32x2u p2 = *(const f32x2u*)(row + a);
                    v[e] = wa * p2.x + wb * p2.y;
                }
            }
            bf16x8 Bv;
#pragma unroll
            for (int e = 0; e < 8; ++e) Bv[e] = (short)f2bf(v[e]);
            *(bf16x8*)&Bl[p][w][k][l * 8] = Bv;
        }

        // --- issue next window's loads (T14; consumer section has no VMEM) ---
        float4 stg[3];
        if (cc < 3) {
            const float* src = xb + (size_t)(cb + 32) * 4096;
#pragma unroll
            for (int it = 0; it < 3; ++it) {
                int idx = it * 512 + t;
                if (idx < 1280) {
                    int r  = idx / 40;
                    int cp = idx - r * 40;
                    stg[it] = *(const float4*)(src + (size_t)r * 4096 + wsod + cp * 4);
                }
            }
        }
        __syncthreads();                            // B[p] ready; interp reads of win done

        // --- consumer: pure LDS + MFMA (stage loads in flight underneath) ---
#pragma unroll
        for (int f = 0; f < 8; ++f) {
#pragma unroll
            for (int k = 0; k < 3; ++k) {
                bf16x8 Bv = *(const bf16x8*)&Bl[p][f][k][l * 8];
                acc[f] = __builtin_amdgcn_mfma_f32_16x16x32_bf16(Areg[k], Bv, acc[f], 0, 0, 0);
            }
        }

        // --- write staged window, one barrier closes the phase ---
        if (cc < 3) {
#pragma unroll
            for (int it = 0; it < 3; ++it) {
                int idx = it * 512 + t;
                if (idx < 1280) {
                    int r  = idx / 40;
                    int cp = idx - r * 40;
                    float* dst = &win[r * WPAD + cp * 4];
                    dst[0] = stg[it].x; dst[1] = stg[it].y;
                    dst[2] = stg[it].z; dst[3] = stg[it].w;
                }
            }
            __syncthreads();
        }
    }

    // C layout: col = lane&15, row = (lane>>4)*4 + reg. Wave w -> o rows w*16..+15.
    int r0 = q * 4;
#pragma unroll
    for (int f = 0; f < 8; ++f) {
#pragma unroll
        for (int r = 0; r < 4; ++r) {
            int o = w * 16 + r0 + r;
            out[((size_t)(b * 128 + o)) * 4096 + i0t + f * 16 + il] = acc[f][r];
        }
    }
}

extern "C" void kernel_launch(void* const* d_in, const int* in_sizes, int n_in,
                              void* d_out, int out_size, void* d_ws, size_t ws_size,
                              hipStream_t stream) {
    const float* x     = (const float*)d_in[0];
    const float* w_off = (const float*)d_in[1];
    const float* b_off = (const float*)d_in[2];
    const float* w_mod = (const float*)d_in[3];
    const float* b_mod = (const float*)d_in[4];
    const float* w_reg = (const float*)d_in[5];
    float* out = (float*)d_out;

    char* ws = (char*)d_ws;
    unsigned short* WrA = (unsigned short*)(ws);
    float* wT    = (float*)(ws + 98304);
    int*   addr2 = (int*)  (ws + 131072);
    float* wae   = (float*)(ws + 1703936);
    float* wbe   = (float*)(ws + 3276800);

    k_wra<<<206, 256, 0, stream>>>(w_reg, w_off, w_mod, WrA, wT);
    k_prep<<<dim3(32, 32), 512, 0, stream>>>(x, wT, b_off, b_mod,
                                             addr2, wae, wbe);
    k_fused<<<dim3(32, 32), 512, 0, stream>>>(WrA, x, addr2, wae, wbe, out);
}